// Round 1
// baseline (701.279 us; speedup 1.0000x reference)
//
#include <hip/hip_runtime.h>
#include <math.h>

#define B_ 16
#define H_ 256
#define L_ 4096
#define N_ 64
#define HN (H_*N_)
#define HL (H_*L_)
#define BHL (B_*H_*L_)

// ---------------------------------------------------------------------------
// Kernel 1: per-(h,n) discretization params
// P layout: [0]=w_re, [1]=w_im, [2]=c2r(fwd), [3]=c2i(fwd), [4]=c2r(bwd), [5]=c2i(bwd)
// each HN floats. c2 = 2 * C * (exp(dtA)-1)/A
// ---------------------------------------------------------------------------
__global__ void params_kernel(const float* __restrict__ log_dt,
                              const float* __restrict__ A_re,
                              const float* __restrict__ A_im,
                              const float* __restrict__ C_re,
                              const float* __restrict__ C_im,
                              float* __restrict__ P) {
    int i = blockIdx.x * blockDim.x + threadIdx.x;  // i = h*64 + n
    if (i >= HN) return;
    int h = i >> 6;
    float dt  = expf(log_dt[h]);
    float Are = A_re[i], Aim = A_im[i];
    float dr = dt * Are, di = dt * Aim;
    float er = expf(dr);
    float wr = er * cosf(di);
    float wi = er * sinf(di);
    // (w - 1) / A  = (w-1) * conj(A) / |A|^2
    float em1r = wr - 1.0f, em1i = wi;
    float inv = 1.0f / (Are*Are + Aim*Aim);
    float qr = (em1r*Are + em1i*Aim) * inv;
    float qi = (em1i*Are - em1r*Aim) * inv;
    P[i]        = wr;
    P[HN + i]   = wi;
    #pragma unroll
    for (int d = 0; d < 2; ++d) {
        float Cr = C_re[d*HN + i], Ci = C_im[d*HN + i];
        P[(2 + 2*d)*HN + i] = 2.0f*(Cr*qr - Ci*qi);
        P[(3 + 2*d)*HN + i] = 2.0f*(Cr*qi + Ci*qr);
    }
}

// ---------------------------------------------------------------------------
// Kernel 2: LayerNorm over channel dim H for each (b,l). Block: (b, 256 l's).
// thread t: hq = t>>6 owns h-range [hq*64, hq*64+64), lo = t&63 owns 4 l's.
// ---------------------------------------------------------------------------
__global__ void __launch_bounds__(256) ln_kernel(const float* __restrict__ x,
                                                 const float* __restrict__ lnw,
                                                 const float* __restrict__ lnb,
                                                 float* __restrict__ z) {
    int b  = blockIdx.y;
    int l0 = blockIdx.x * 256;
    int t  = threadIdx.x;
    int hq = t >> 6, lo = t & 63;
    int l  = l0 + lo * 4;
    __shared__ float4 r1[4][64];
    __shared__ float4 r2[4][64];
    __shared__ float4 muS[64];
    __shared__ float4 rsS[64];
    const float* xb = x + (size_t)b * HL;
    float4 s1 = {0.f,0.f,0.f,0.f}, s2 = {0.f,0.f,0.f,0.f};
    #pragma unroll 4
    for (int hh = 0; hh < 64; ++hh) {
        int h = hq * 64 + hh;
        float4 v = *(const float4*)(xb + (size_t)h * L_ + l);
        s1.x += v.x; s1.y += v.y; s1.z += v.z; s1.w += v.w;
        s2.x += v.x*v.x; s2.y += v.y*v.y; s2.z += v.z*v.z; s2.w += v.w*v.w;
    }
    r1[hq][lo] = s1; r2[hq][lo] = s2;
    __syncthreads();
    if (t < 64) {
        float4 S1 = r1[0][t], S2 = r2[0][t];
        #pragma unroll
        for (int q = 1; q < 4; ++q) {
            float4 a = r1[q][t], c = r2[q][t];
            S1.x += a.x; S1.y += a.y; S1.z += a.z; S1.w += a.w;
            S2.x += c.x; S2.y += c.y; S2.z += c.z; S2.w += c.w;
        }
        const float invH = 1.0f / 256.0f;
        float4 mu, rs;
        mu.x = S1.x*invH; mu.y = S1.y*invH; mu.z = S1.z*invH; mu.w = S1.w*invH;
        rs.x = rsqrtf(S2.x*invH - mu.x*mu.x + 1e-5f);
        rs.y = rsqrtf(S2.y*invH - mu.y*mu.y + 1e-5f);
        rs.z = rsqrtf(S2.z*invH - mu.z*mu.z + 1e-5f);
        rs.w = rsqrtf(S2.w*invH - mu.w*mu.w + 1e-5f);
        muS[t] = mu; rsS[t] = rs;
    }
    __syncthreads();
    float4 mu = muS[lo], rs = rsS[lo];
    #pragma unroll 4
    for (int hh = 0; hh < 64; ++hh) {
        int h = hq * 64 + hh;
        float w = lnw[h], bb = lnb[h];
        float4 v = *(const float4*)(xb + (size_t)h * L_ + l);
        float4 zz;
        zz.x = (v.x - mu.x) * rs.x * w + bb;
        zz.y = (v.y - mu.y) * rs.y * w + bb;
        zz.z = (v.z - mu.z) * rs.z * w + bb;
        zz.w = (v.w - mu.w) * rs.w * w + bb;
        *(float4*)(z + (size_t)b * HL + (size_t)h * L_ + l) = zz;
    }
}

// ---------------------------------------------------------------------------
// Kernel 3: bidirectional S4D recurrence. 1 block per (b,h), 128 threads:
// tid 0..63  = forward,  mode n = tid       (wave 0)
// tid 64..127= backward, mode n = tid-64    (wave 1)
// Chunked by 32 steps; contributions buffered in LDS then reduced over modes.
// ---------------------------------------------------------------------------
#define SSTEP(zc, jidx)                                                    \
    {                                                                      \
        float nr_ = fmaf(wr, sr, fmaf(-wi, si, (zc)));                     \
        float ni_ = fmaf(wr, si, wi * sr);                                 \
        sr = nr_; si = ni_;                                                \
        contrib[t][(jidx)] = fmaf(cr, sr, -(ci * si));                     \
    }
#define BSTEP(zc, jidx)                                                    \
    {                                                                      \
        contrib[t][(jidx)] = fmaf(cr, sr, -(ci * si));                     \
        float nr_ = fmaf(wr, sr, fmaf(-wi, si, (zc)));                     \
        float ni_ = fmaf(wr, si, wi * sr);                                 \
        sr = nr_; si = ni_;                                                \
    }

__global__ void __launch_bounds__(128) ssm_kernel(const float* __restrict__ z,
                                                  const float* __restrict__ P,
                                                  float* __restrict__ yf,
                                                  float* __restrict__ yb) {
    int bh = blockIdx.x;
    int h  = bh & (H_ - 1);
    int t  = threadIdx.x;
    int n  = t & 63;
    int dir = t >> 6;
    int pi = h * 64 + n;
    float wr = P[pi];
    float wi = P[HN + pi];
    float cr = P[(2 + 2*dir)*HN + pi];
    float ci = P[(3 + 2*dir)*HN + pi];
    const float* zr = z + (size_t)bh * L_;
    __shared__ float contrib[128][33];
    float sr = 0.f, si = 0.f;
    const int Nc = L_ / 32;
    for (int c = 0; c < Nc; ++c) {
        if (dir == 0) {
            int base = c * 32;
            #pragma unroll
            for (int jj = 0; jj < 32; jj += 4) {
                float4 zv = *(const float4*)(zr + base + jj);
                SSTEP(zv.x, jj + 0);
                SSTEP(zv.y, jj + 1);
                SSTEP(zv.z, jj + 2);
                SSTEP(zv.w, jj + 3);
            }
        } else {
            int base = (Nc - 1 - c) * 32;
            #pragma unroll
            for (int jj = 28; jj >= 0; jj -= 4) {
                float4 zv = *(const float4*)(zr + base + jj);
                BSTEP(zv.w, jj + 3);
                BSTEP(zv.z, jj + 2);
                BSTEP(zv.y, jj + 1);
                BSTEP(zv.x, jj + 0);
            }
        }
        __syncthreads();
        // reduce over 64 mode-rows for this direction's chunk
        int j = t & 31;
        int half = (t >> 5) & 1;
        int rbase = (dir << 6) + (half << 5);
        float acc = 0.f;
        #pragma unroll 8
        for (int r = 0; r < 32; ++r) acc += contrib[rbase + r][j];
        acc += __shfl_xor(acc, 32, 64);
        if (half == 0) {
            if (dir == 0) yf[(size_t)bh * L_ + c * 32 + j] = acc;
            else          yb[(size_t)bh * L_ + (Nc - 1 - c) * 32 + j] = acc;
        }
        __syncthreads();
    }
}

// ---------------------------------------------------------------------------
// Kernel 4: g = gelu_tanh(yf + yb + D[h]*z), written in-place into yf.
// ---------------------------------------------------------------------------
__global__ void combine_kernel(const float* __restrict__ yb,
                               const float* __restrict__ zz,
                               const float* __restrict__ D,
                               float* __restrict__ yf) {
    const int total4 = BHL / 4;
    for (int i = blockIdx.x * blockDim.x + threadIdx.x; i < total4;
         i += gridDim.x * blockDim.x) {
        size_t base = (size_t)i * 4;
        int h = (int)((base >> 12) & (H_ - 1));
        float d = D[h];
        float4 a = ((const float4*)yf)[i];
        float4 bq = ((const float4*)yb)[i];
        float4 zv = ((const float4*)zz)[i];
        float v[4] = { a.x + bq.x + d * zv.x, a.y + bq.y + d * zv.y,
                       a.z + bq.z + d * zv.z, a.w + bq.w + d * zv.w };
        float g[4];
        #pragma unroll
        for (int k = 0; k < 4; ++k) {
            float u = v[k];
            float inner = 0.7978845608028654f * (u + 0.044715f * u * u * u);
            g[k] = 0.5f * u * (1.0f + tanhf(inner));
        }
        float4 o; o.x = g[0]; o.y = g[1]; o.z = g[2]; o.w = g[3];
        ((float4*)yf)[i] = o;
    }
}

// ---------------------------------------------------------------------------
// Kernel 5: out[b,o,l] = x[b,o,l] + b_out[o] + sum_h W[o,h]*g[b,h,l]
// fp32 LDS-tiled GEMM, 64x64 output tile, 256 threads, 4x4 per thread.
// ---------------------------------------------------------------------------
__global__ void __launch_bounds__(256) outproj_kernel(const float* __restrict__ g,
                                                      const float* __restrict__ x,
                                                      const float* __restrict__ W,
                                                      const float* __restrict__ bias,
                                                      float* __restrict__ out) {
    int b  = blockIdx.z;
    int o0 = blockIdx.y * 64;
    int l0 = blockIdx.x * 64;
    int t  = threadIdx.x;
    __shared__ float Ws[16][68];  // [k][o], padded for alignment + banks
    __shared__ float Gs[16][64];  // [k][l]
    float acc[4][4];
    #pragma unroll
    for (int i = 0; i < 4; ++i)
        #pragma unroll
        for (int j = 0; j < 4; ++j) acc[i][j] = 0.f;
    int to = (t >> 4) << 2;
    int tl = (t & 15) << 2;
    int wrow = t >> 2;
    int wcg  = (t & 3) << 2;
    int grow = t >> 4;
    for (int h0 = 0; h0 < H_; h0 += 16) {
        float4 wv = *(const float4*)(W + (size_t)(o0 + wrow) * H_ + h0 + wcg);
        float4 gv = *(const float4*)(g + ((size_t)(b * H_ + h0 + grow)) * L_ + l0 + tl);
        __syncthreads();
        Ws[wcg + 0][wrow] = wv.x;
        Ws[wcg + 1][wrow] = wv.y;
        Ws[wcg + 2][wrow] = wv.z;
        Ws[wcg + 3][wrow] = wv.w;
        *(float4*)&Gs[grow][tl] = gv;
        __syncthreads();
        #pragma unroll
        for (int kk = 0; kk < 16; ++kk) {
            float4 a4 = *(const float4*)&Ws[kk][to];
            float4 b4 = *(const float4*)&Gs[kk][tl];
            float av[4] = {a4.x, a4.y, a4.z, a4.w};
            float bv[4] = {b4.x, b4.y, b4.z, b4.w};
            #pragma unroll
            for (int ii = 0; ii < 4; ++ii)
                #pragma unroll
                for (int ji = 0; ji < 4; ++ji)
                    acc[ii][ji] = fmaf(av[ii], bv[ji], acc[ii][ji]);
        }
    }
    #pragma unroll
    for (int ii = 0; ii < 4; ++ii) {
        int o = o0 + to + ii;
        float bo = bias[o];
        size_t off = ((size_t)(b * H_ + o)) * L_ + l0 + tl;
        float4 xr = *(const float4*)(x + off);
        float4 ov;
        ov.x = xr.x + bo + acc[ii][0];
        ov.y = xr.y + bo + acc[ii][1];
        ov.z = xr.z + bo + acc[ii][2];
        ov.w = xr.w + bo + acc[ii][3];
        *(float4*)(out + off) = ov;
    }
}

// ---------------------------------------------------------------------------
extern "C" void kernel_launch(void* const* d_in, const int* in_sizes, int n_in,
                              void* d_out, int out_size, void* d_ws, size_t ws_size,
                              hipStream_t stream) {
    const float* x      = (const float*)d_in[0];
    const float* log_dt = (const float*)d_in[1];
    const float* A_re   = (const float*)d_in[2];
    const float* A_im   = (const float*)d_in[3];
    const float* C_re   = (const float*)d_in[4];
    const float* C_im   = (const float*)d_in[5];
    const float* D      = (const float*)d_in[6];
    const float* lnw    = (const float*)d_in[7];
    const float* lnb    = (const float*)d_in[8];
    const float* W      = (const float*)d_in[9];
    const float* bout   = (const float*)d_in[10];
    float* out = (float*)d_out;
    float* ws  = (float*)d_ws;

    float* z  = ws;                        // BHL
    float* yf = ws + (size_t)BHL;          // BHL (later reused as g)
    float* P  = ws + 2 * (size_t)BHL;      // 6*HN
    float* yb = out;                       // reuse output buffer as bwd scratch

    params_kernel<<<(HN + 255) / 256, 256, 0, stream>>>(log_dt, A_re, A_im, C_re, C_im, P);
    ln_kernel<<<dim3(L_ / 256, B_), 256, 0, stream>>>(x, lnw, lnb, z);
    ssm_kernel<<<B_ * H_, 128, 0, stream>>>(z, P, yf, yb);
    combine_kernel<<<2048, 256, 0, stream>>>(yb, z, D, yf);
    outproj_kernel<<<dim3(L_ / 64, H_ / 64, B_), 256, 0, stream>>>(yf, x, W, bout, out);
}